// Round 3
// baseline (128.037 us; speedup 1.0000x reference)
//
#include <hip/hip_runtime.h>

// Fused tanh-RNN (T=64, I=64, H=100) + tanh + linear (C=40), B=16384.
// TRANSPOSED formulation: D = A*B with A = weight fragments (register-resident),
// B = data^T (x / h). W_hh columns are pre-permuted by
//   phi(32kb+8g+e) = 32kb + 16*(e>>2) + 4g + (e&3)
// so the MFMA D-output registers ARE the next step's B-fragment after a
// per-lane f16 convert: no LDS, no cross-lane traffic, no barriers.
// One wave owns 16 batch rows for all 64 steps; 1024 waves = 1 wave/SIMD.
//
// Round-3 change: UNCONDITIONAL clamped prefetch (min(t+2,63)) so the loop has
// a constant outstanding-VMEM structure -> compiler can emit counted vmcnt(N)
// instead of vmcnt(0) (the conditional prefetch forced a full drain per step,
// serializing compute with memory). + unroll 2 to kill register rotation.

typedef _Float16 half8 __attribute__((ext_vector_type(8)));
typedef float float4_t __attribute__((ext_vector_type(4)));

__device__ __forceinline__ float tanh_fast(float x) {
  // tanh(x) = 1 - 2/(exp2(2x*log2e)+1); exact at +-inf
  float e = __builtin_amdgcn_exp2f(x * 2.8853900817779268f);
  return 1.0f - 2.0f * __builtin_amdgcn_rcpf(e + 1.0f);
}

__global__ __launch_bounds__(256, 1) void rnn_fused(
    const float* __restrict__ x, const float* __restrict__ W_ih,
    const float* __restrict__ W_hh, const float* __restrict__ b_ih,
    const float* __restrict__ b_hh, const float* __restrict__ fc_W,
    const float* __restrict__ fc_b, float* __restrict__ out, int B)
{
  const int lane = threadIdx.x & 63;
  const int wave = threadIdx.x >> 6;
  const int g = lane >> 4;   // k-group / D-row group
  const int c = lane & 15;   // batch col (B,D) == weight row (A)
  const int rowbase = (blockIdx.x * 4 + wave) * 16;

  // ---- A-fragment weights, register-resident.
  // A-frag (16x16x32): lane (g,c) element e holds A[m=c][k=8g+e].
  half8 wih[2][7];    // W_ih[16nt+c][32kb+8g+e]           (k = input dim, no perm)
  half8 whh[4][7];    // W_hh[16nt+c][phi(32kb+8g+e)]      (k = h dim, permuted)
  float4_t bias[7];   // (b_ih+b_hh)[16nt+4g+v]            (matches D layout)

  #pragma unroll
  for (int nt = 0; nt < 7; ++nt) {
    int nb = nt * 16 + 4 * g;
    float4_t bi = {0.f, 0.f, 0.f, 0.f};
    if (nb + 3 < 100) {
      float4_t a = *(const float4_t*)(b_ih + nb);
      float4_t b = *(const float4_t*)(b_hh + nb);
      bi = a + b;
    }
    bias[nt] = bi;

    int nrow = nt * 16 + c;
    bool rv = (nrow < 100);
    #pragma unroll
    for (int kb = 0; kb < 2; ++kb) {
      float4_t f0 = {0.f,0.f,0.f,0.f}, f1 = {0.f,0.f,0.f,0.f};
      if (rv) {
        const float* p = W_ih + nrow * 64 + kb * 32 + g * 8;
        f0 = *(const float4_t*)p;
        f1 = *(const float4_t*)(p + 4);
      }
      half8 h;
      #pragma unroll
      for (int j = 0; j < 4; ++j) { h[j] = (_Float16)f0[j]; h[4 + j] = (_Float16)f1[j]; }
      wih[kb][nt] = h;
    }
    #pragma unroll
    for (int kb = 0; kb < 4; ++kb) {
      // phi: elements 0..3 -> cols 32kb+4g+0..3 ; elements 4..7 -> cols 32kb+16+4g+0..3
      int clo = kb * 32 + 4 * g;
      int chi = clo + 16;
      float4_t f0 = {0.f,0.f,0.f,0.f}, f1 = {0.f,0.f,0.f,0.f};
      if (rv && clo + 3 < 100) f0 = *(const float4_t*)(W_hh + nrow * 100 + clo);
      if (rv && chi + 3 < 100) f1 = *(const float4_t*)(W_hh + nrow * 100 + chi);
      half8 h;
      #pragma unroll
      for (int j = 0; j < 4; ++j) { h[j] = (_Float16)f0[j]; h[4 + j] = (_Float16)f1[j]; }
      whh[kb][nt] = h;
    }
  }

  // ---- x streaming: lane (g,c) reads batch row (rowbase+c),
  // per step 16 floats at k = 8g..8g+7 and 32+8g..32+8g+7  (= x B-fragment).
  const float* xrow = x + (size_t)(rowbase + c) * 4096 + g * 8;
  float4_t s0, s1, s2, s3;   // x_t
  float4_t p0, p1, p2, p3;   // x_{t+1}
  {
    const float* p = xrow;
    s0 = *(const float4_t*)p;        s1 = *(const float4_t*)(p + 4);
    s2 = *(const float4_t*)(p + 32); s3 = *(const float4_t*)(p + 36);
    p += 64;
    p0 = *(const float4_t*)p;        p1 = *(const float4_t*)(p + 4);
    p2 = *(const float4_t*)(p + 32); p3 = *(const float4_t*)(p + 36);
  }

  float4_t acc[7];
  half8 hfrag[4];
  #pragma unroll
  for (int kb = 0; kb < 4; ++kb) hfrag[kb] = (half8)(_Float16)0.0f;  // h_0 = 0

  #pragma unroll 2
  for (int t = 0; t < 64; ++t) {
    // UNCONDITIONAL clamped prefetch of x_{t+2}: constant VMEM structure ->
    // counted vmcnt instead of a per-step vmcnt(0) drain. Tail re-reads x_63
    // (L1 hit, discarded by rotation).
    int tp = (t + 2 < 63) ? (t + 2) : 63;
    const float* pp = xrow + tp * 64;
    float4_t q0 = *(const float4_t*)pp;
    float4_t q1 = *(const float4_t*)(pp + 4);
    float4_t q2 = *(const float4_t*)(pp + 32);
    float4_t q3 = *(const float4_t*)(pp + 36);

    // x B-frags (f16)
    half8 xb0, xb1;
    #pragma unroll
    for (int j = 0; j < 4; ++j) {
      xb0[j] = (_Float16)s0[j]; xb0[4 + j] = (_Float16)s1[j];
      xb1[j] = (_Float16)s2[j]; xb1[4 + j] = (_Float16)s3[j];
    }

    // preact = bias + W_ih x_t^T + W_hh h_t^T
    #pragma unroll
    for (int nt = 0; nt < 7; ++nt) {
      acc[nt] = __builtin_amdgcn_mfma_f32_16x16x32_f16(wih[0][nt], xb0, bias[nt], 0, 0, 0);
      acc[nt] = __builtin_amdgcn_mfma_f32_16x16x32_f16(wih[1][nt], xb1, acc[nt], 0, 0, 0);
    }
    #pragma unroll
    for (int kb = 0; kb < 4; ++kb)
      #pragma unroll
      for (int nt = 0; nt < 7; ++nt)
        acc[nt] = __builtin_amdgcn_mfma_f32_16x16x32_f16(whh[kb][nt], hfrag[kb], acc[nt], 0, 0, 0);

    // h_{t+1} = tanh(preact); D regs -> next B-frag via per-lane cvt only
    #pragma unroll
    for (int nt = 0; nt < 7; ++nt)
      #pragma unroll
      for (int v = 0; v < 4; ++v)
        acc[nt][v] = tanh_fast(acc[nt][v]);

    #pragma unroll
    for (int kb = 0; kb < 4; ++kb) {
      half8 h;
      #pragma unroll
      for (int v = 0; v < 4; ++v) {
        h[v] = (_Float16)acc[2 * kb][v];
        h[4 + v] = (kb < 3) ? (_Float16)acc[2 * kb + 1][v] : (_Float16)0.0f;
      }
      hfrag[kb] = h;
    }

    s0 = p0; s1 = p1; s2 = p2; s3 = p3;
    p0 = q0; p1 = q1; p2 = q2; p3 = q3;
  }

  // ---- epilogue: out^T = fc_W * tanh(h_last)^T + fc_b
  #pragma unroll
  for (int nt = 0; nt < 7; ++nt)
    #pragma unroll
    for (int v = 0; v < 4; ++v)
      acc[nt][v] = tanh_fast(acc[nt][v]);
  #pragma unroll
  for (int kb = 0; kb < 4; ++kb) {
    half8 h;
    #pragma unroll
    for (int v = 0; v < 4; ++v) {
      h[v] = (_Float16)acc[2 * kb][v];
      h[4 + v] = (kb < 3) ? (_Float16)acc[2 * kb + 1][v] : (_Float16)0.0f;
    }
    hfrag[kb] = h;
  }

  half8 wfc[4][3];
  float4_t bfc[3];
  #pragma unroll
  for (int nt = 0; nt < 3; ++nt) {
    int nb = nt * 16 + 4 * g;
    float4_t bi = {0.f,0.f,0.f,0.f};
    if (nb + 3 < 40) bi = *(const float4_t*)(fc_b + nb);
    bfc[nt] = bi;

    int nrow = nt * 16 + c;
    bool rv = (nrow < 40);
    #pragma unroll
    for (int kb = 0; kb < 4; ++kb) {
      int clo = kb * 32 + 4 * g;
      int chi = clo + 16;
      float4_t f0 = {0.f,0.f,0.f,0.f}, f1 = {0.f,0.f,0.f,0.f};
      if (rv && clo + 3 < 100) f0 = *(const float4_t*)(fc_W + nrow * 100 + clo);
      if (rv && chi + 3 < 100) f1 = *(const float4_t*)(fc_W + nrow * 100 + chi);
      half8 h;
      #pragma unroll
      for (int j = 0; j < 4; ++j) { h[j] = (_Float16)f0[j]; h[4 + j] = (_Float16)f1[j]; }
      wfc[kb][nt] = h;
    }
  }

  float4_t oacc[3];
  #pragma unroll
  for (int nt = 0; nt < 3; ++nt) oacc[nt] = bfc[nt];
  #pragma unroll
  for (int kb = 0; kb < 4; ++kb)
    #pragma unroll
    for (int nt = 0; nt < 3; ++nt)
      oacc[nt] = __builtin_amdgcn_mfma_f32_16x16x32_f16(wfc[kb][nt], hfrag[kb], oacc[nt], 0, 0, 0);

  // store: lane (g,c) holds out[rowbase+c][n = 16nt+4g+v]
  #pragma unroll
  for (int nt = 0; nt < 3; ++nt)
    #pragma unroll
    for (int v = 0; v < 4; ++v) {
      int n = nt * 16 + 4 * g + v;
      if (n < 40)
        out[(size_t)(rowbase + c) * 40 + n] = oacc[nt][v];
    }
}

extern "C" void kernel_launch(void* const* d_in, const int* in_sizes, int n_in,
                              void* d_out, int out_size, void* d_ws, size_t ws_size,
                              hipStream_t stream) {
  const float* x    = (const float*)d_in[0];
  const float* W_ih = (const float*)d_in[1];
  const float* W_hh = (const float*)d_in[2];
  const float* b_ih = (const float*)d_in[3];
  const float* b_hh = (const float*)d_in[4];
  const float* fc_W = (const float*)d_in[5];
  const float* fc_b = (const float*)d_in[6];
  float* outp = (float*)d_out;

  int B = in_sizes[0] / 4096;      // 16384
  int grid = (B + 63) / 64;        // 64 batch rows per 4-wave block
  rnn_fused<<<grid, 256, 0, stream>>>(x, W_ih, W_hh, b_ih, b_hh, fc_W, fc_b, outp, B);
}

// Round 4
// 109.966 us; speedup vs baseline: 1.1643x; 1.1643x over previous
//
#include <hip/hip_runtime.h>

// Fused tanh-RNN (T=64, I=64, H=100) + tanh + linear (C=40), B=16384.
// TRANSPOSED formulation: D = A*B with A = weight fragments (register-resident),
// B = data^T (x / h). W_hh columns are pre-permuted by
//   phi(32kb+8g+e) = 32kb + 16*(e>>2) + 4g + (e&3)
// so the MFMA D-output registers ARE the next step's B-fragment after a
// per-lane f16 convert: no LDS, no cross-lane traffic, no barriers.
// One wave owns 16 batch rows for all 64 steps; 1024 waves = 1 wave/SIMD.
//
// Round-4: NO unroll pragma (r3's unroll-2 caused VGPR collapse to 192 +
// spills -> 128us). Keep unconditional branch-free clamped prefetch, deepened
// to 3 steps (12 loads in flight -> counted vmcnt, latency hidden under ~2
// steps of compute).

typedef _Float16 half8 __attribute__((ext_vector_type(8)));
typedef float float4_t __attribute__((ext_vector_type(4)));

__device__ __forceinline__ float tanh_fast(float x) {
  // tanh(x) = 1 - 2/(exp2(2x*log2e)+1); exact at +-inf
  float e = __builtin_amdgcn_exp2f(x * 2.8853900817779268f);
  return 1.0f - 2.0f * __builtin_amdgcn_rcpf(e + 1.0f);
}

__global__ __launch_bounds__(256, 1) void rnn_fused(
    const float* __restrict__ x, const float* __restrict__ W_ih,
    const float* __restrict__ W_hh, const float* __restrict__ b_ih,
    const float* __restrict__ b_hh, const float* __restrict__ fc_W,
    const float* __restrict__ fc_b, float* __restrict__ out, int B)
{
  const int lane = threadIdx.x & 63;
  const int wave = threadIdx.x >> 6;
  const int g = lane >> 4;   // k-group / D-row group
  const int c = lane & 15;   // batch col (B,D) == weight row (A)
  const int rowbase = (blockIdx.x * 4 + wave) * 16;

  // ---- A-fragment weights, register-resident.
  // A-frag (16x16x32): lane (g,c) element e holds A[m=c][k=8g+e].
  half8 wih[2][7];    // W_ih[16nt+c][32kb+8g+e]           (k = input dim, no perm)
  half8 whh[4][7];    // W_hh[16nt+c][phi(32kb+8g+e)]      (k = h dim, permuted)
  float4_t bias[7];   // (b_ih+b_hh)[16nt+4g+v]            (matches D layout)

  #pragma unroll
  for (int nt = 0; nt < 7; ++nt) {
    int nb = nt * 16 + 4 * g;
    float4_t bi = {0.f, 0.f, 0.f, 0.f};
    if (nb + 3 < 100) {
      float4_t a = *(const float4_t*)(b_ih + nb);
      float4_t b = *(const float4_t*)(b_hh + nb);
      bi = a + b;
    }
    bias[nt] = bi;

    int nrow = nt * 16 + c;
    bool rv = (nrow < 100);
    #pragma unroll
    for (int kb = 0; kb < 2; ++kb) {
      float4_t f0 = {0.f,0.f,0.f,0.f}, f1 = {0.f,0.f,0.f,0.f};
      if (rv) {
        const float* p = W_ih + nrow * 64 + kb * 32 + g * 8;
        f0 = *(const float4_t*)p;
        f1 = *(const float4_t*)(p + 4);
      }
      half8 h;
      #pragma unroll
      for (int j = 0; j < 4; ++j) { h[j] = (_Float16)f0[j]; h[4 + j] = (_Float16)f1[j]; }
      wih[kb][nt] = h;
    }
    #pragma unroll
    for (int kb = 0; kb < 4; ++kb) {
      // phi: elements 0..3 -> cols 32kb+4g+0..3 ; elements 4..7 -> cols 32kb+16+4g+0..3
      int clo = kb * 32 + 4 * g;
      int chi = clo + 16;
      float4_t f0 = {0.f,0.f,0.f,0.f}, f1 = {0.f,0.f,0.f,0.f};
      if (rv && clo + 3 < 100) f0 = *(const float4_t*)(W_hh + nrow * 100 + clo);
      if (rv && chi + 3 < 100) f1 = *(const float4_t*)(W_hh + nrow * 100 + chi);
      half8 h;
      #pragma unroll
      for (int j = 0; j < 4; ++j) { h[j] = (_Float16)f0[j]; h[4 + j] = (_Float16)f1[j]; }
      whh[kb][nt] = h;
    }
  }

  // ---- x streaming: lane (g,c) reads batch row (rowbase+c),
  // per step 16 floats at k = 8g..8g+7 and 32+8g..32+8g+7  (= x B-fragment).
  const float* xrow = x + (size_t)(rowbase + c) * 4096 + g * 8;
  float4_t s0, s1, s2, s3;   // x_t
  float4_t p0, p1, p2, p3;   // x_{t+1}
  float4_t q0, q1, q2, q3;   // x_{t+2}
  {
    const float* p = xrow;
    s0 = *(const float4_t*)p;        s1 = *(const float4_t*)(p + 4);
    s2 = *(const float4_t*)(p + 32); s3 = *(const float4_t*)(p + 36);
    p += 64;
    p0 = *(const float4_t*)p;        p1 = *(const float4_t*)(p + 4);
    p2 = *(const float4_t*)(p + 32); p3 = *(const float4_t*)(p + 36);
    p += 64;
    q0 = *(const float4_t*)p;        q1 = *(const float4_t*)(p + 4);
    q2 = *(const float4_t*)(p + 32); q3 = *(const float4_t*)(p + 36);
  }

  float4_t acc[7];
  half8 hfrag[4];
  #pragma unroll
  for (int kb = 0; kb < 4; ++kb) hfrag[kb] = (half8)(_Float16)0.0f;  // h_0 = 0

  for (int t = 0; t < 64; ++t) {
    // UNCONDITIONAL clamped prefetch of x_{t+3}: issued every iteration with a
    // branch-free (scalar-select) address -> constant outstanding-VMEM count ->
    // counted vmcnt instead of a per-step vmcnt(0) drain. Tail re-reads x_63
    // (L1 hit, value discarded by rotation).
    int tp = t + 3; if (tp > 63) tp = 63;
    const float* pp = xrow + tp * 64;
    float4_t r0 = *(const float4_t*)pp;
    float4_t r1 = *(const float4_t*)(pp + 4);
    float4_t r2 = *(const float4_t*)(pp + 32);
    float4_t r3 = *(const float4_t*)(pp + 36);

    // x B-frags (f16)
    half8 xb0, xb1;
    #pragma unroll
    for (int j = 0; j < 4; ++j) {
      xb0[j] = (_Float16)s0[j]; xb0[4 + j] = (_Float16)s1[j];
      xb1[j] = (_Float16)s2[j]; xb1[4 + j] = (_Float16)s3[j];
    }

    // preact = bias + W_ih x_t^T + W_hh h_t^T
    #pragma unroll
    for (int nt = 0; nt < 7; ++nt) {
      acc[nt] = __builtin_amdgcn_mfma_f32_16x16x32_f16(wih[0][nt], xb0, bias[nt], 0, 0, 0);
      acc[nt] = __builtin_amdgcn_mfma_f32_16x16x32_f16(wih[1][nt], xb1, acc[nt], 0, 0, 0);
    }
    #pragma unroll
    for (int kb = 0; kb < 4; ++kb)
      #pragma unroll
      for (int nt = 0; nt < 7; ++nt)
        acc[nt] = __builtin_amdgcn_mfma_f32_16x16x32_f16(whh[kb][nt], hfrag[kb], acc[nt], 0, 0, 0);

    // h_{t+1} = tanh(preact); D regs -> next B-frag via per-lane cvt only
    #pragma unroll
    for (int nt = 0; nt < 7; ++nt)
      #pragma unroll
      for (int v = 0; v < 4; ++v)
        acc[nt][v] = tanh_fast(acc[nt][v]);

    #pragma unroll
    for (int kb = 0; kb < 4; ++kb) {
      half8 h;
      #pragma unroll
      for (int v = 0; v < 4; ++v) {
        h[v] = (_Float16)acc[2 * kb][v];
        h[4 + v] = (kb < 3) ? (_Float16)acc[2 * kb + 1][v] : (_Float16)0.0f;
      }
      hfrag[kb] = h;
    }

    s0 = p0; s1 = p1; s2 = p2; s3 = p3;
    p0 = q0; p1 = q1; p2 = q2; p3 = q3;
    q0 = r0; q1 = r1; q2 = r2; q3 = r3;
  }

  // ---- epilogue: out^T = fc_W * tanh(h_last)^T + fc_b
  #pragma unroll
  for (int nt = 0; nt < 7; ++nt)
    #pragma unroll
    for (int v = 0; v < 4; ++v)
      acc[nt][v] = tanh_fast(acc[nt][v]);
  #pragma unroll
  for (int kb = 0; kb < 4; ++kb) {
    half8 h;
    #pragma unroll
    for (int v = 0; v < 4; ++v) {
      h[v] = (_Float16)acc[2 * kb][v];
      h[4 + v] = (kb < 3) ? (_Float16)acc[2 * kb + 1][v] : (_Float16)0.0f;
    }
    hfrag[kb] = h;
  }

  half8 wfc[4][3];
  float4_t bfc[3];
  #pragma unroll
  for (int nt = 0; nt < 3; ++nt) {
    int nb = nt * 16 + 4 * g;
    float4_t bi = {0.f,0.f,0.f,0.f};
    if (nb + 3 < 40) bi = *(const float4_t*)(fc_b + nb);
    bfc[nt] = bi;

    int nrow = nt * 16 + c;
    bool rv = (nrow < 40);
    #pragma unroll
    for (int kb = 0; kb < 4; ++kb) {
      int clo = kb * 32 + 4 * g;
      int chi = clo + 16;
      float4_t f0 = {0.f,0.f,0.f,0.f}, f1 = {0.f,0.f,0.f,0.f};
      if (rv && clo + 3 < 100) f0 = *(const float4_t*)(fc_W + nrow * 100 + clo);
      if (rv && chi + 3 < 100) f1 = *(const float4_t*)(fc_W + nrow * 100 + chi);
      half8 h;
      #pragma unroll
      for (int j = 0; j < 4; ++j) { h[j] = (_Float16)f0[j]; h[4 + j] = (_Float16)f1[j]; }
      wfc[kb][nt] = h;
    }
  }

  float4_t oacc[3];
  #pragma unroll
  for (int nt = 0; nt < 3; ++nt) oacc[nt] = bfc[nt];
  #pragma unroll
  for (int kb = 0; kb < 4; ++kb)
    #pragma unroll
    for (int nt = 0; nt < 3; ++nt)
      oacc[nt] = __builtin_amdgcn_mfma_f32_16x16x32_f16(wfc[kb][nt], hfrag[kb], oacc[nt], 0, 0, 0);

  // store: lane (g,c) holds out[rowbase+c][n = 16nt+4g+v]
  #pragma unroll
  for (int nt = 0; nt < 3; ++nt)
    #pragma unroll
    for (int v = 0; v < 4; ++v) {
      int n = nt * 16 + 4 * g + v;
      if (n < 40)
        out[(size_t)(rowbase + c) * 40 + n] = oacc[nt][v];
    }
}

extern "C" void kernel_launch(void* const* d_in, const int* in_sizes, int n_in,
                              void* d_out, int out_size, void* d_ws, size_t ws_size,
                              hipStream_t stream) {
  const float* x    = (const float*)d_in[0];
  const float* W_ih = (const float*)d_in[1];
  const float* W_hh = (const float*)d_in[2];
  const float* b_ih = (const float*)d_in[3];
  const float* b_hh = (const float*)d_in[4];
  const float* fc_W = (const float*)d_in[5];
  const float* fc_b = (const float*)d_in[6];
  float* outp = (float*)d_out;

  int B = in_sizes[0] / 4096;      // 16384
  int grid = (B + 63) / 64;        // 64 batch rows per 4-wave block
  rnn_fused<<<grid, 256, 0, stream>>>(x, W_ih, W_hh, b_ih, b_hh, fc_W, fc_b, outp, B);
}

// Round 5
// 65.510 us; speedup vs baseline: 1.9545x; 1.6786x over previous
//
#include <hip/hip_runtime.h>

// Fused tanh-RNN (T=64, I=64, H=100) + tanh + linear (C=40), B=16384.
// TRANSPOSED formulation: D = A*B, A = register-resident weight fragments,
// B = data^T (x / h). W_hh columns pre-permuted by
//   phi(32kb+8g+e) = 32kb + 16*(e>>2) + 4g + (e&3)
// so MFMA D-output regs ARE the next step's B-fragment after per-lane f16 cvt.
//
// Round-5: x staged through a wave-private 4-slot LDS ring via
// global_load_lds (16B DMA, 5 issues/step, 3 steps ahead) + ONE manual
// counted s_waitcnt vmcnt(15)/step (never 0). Removes all x-staging VGPRs
// (r3/r4 showed the kernel sits on the VGPR cliff) and decouples load issue
// from consumption. Slot layout: 16 rows x 272B (17 chunks of 16B; chunk 16 =
// pad) -> ds_read_b128 conflict-free. Recurrence MFMAs ordered before the
// input-proj MFMAs so ds_read latency hides under register-fed MFMAs.

typedef _Float16 half8 __attribute__((ext_vector_type(8)));
typedef float float4_t __attribute__((ext_vector_type(4)));

#define SLOT_BYTES 5120   // 5 issues x 1024B (4352 used: 16 rows x 272B)
#define GLOAD16(gp, lp)                                                   \
  __builtin_amdgcn_global_load_lds(                                       \
      (const __attribute__((address_space(1))) void*)(gp),                \
      (__attribute__((address_space(3))) void*)(lp), 16, 0, 0)

__device__ __forceinline__ float tanh_fast(float x) {
  float e = __builtin_amdgcn_exp2f(x * 2.8853900817779268f);
  return 1.0f - 2.0f * __builtin_amdgcn_rcpf(e + 1.0f);
}

__global__ __launch_bounds__(256, 1) void rnn_fused(
    const float* __restrict__ x, const float* __restrict__ W_ih,
    const float* __restrict__ W_hh, const float* __restrict__ b_ih,
    const float* __restrict__ b_hh, const float* __restrict__ fc_W,
    const float* __restrict__ fc_b, float* __restrict__ out, int B)
{
  __shared__ char ring[4][4 * SLOT_BYTES];   // [wave][slot]
  const int lane = threadIdx.x & 63;
  const int wave = threadIdx.x >> 6;
  const int g = lane >> 4;   // k-group / D-row group
  const int c = lane & 15;   // batch col (B,D) == weight row (A)
  const int rowbase = (blockIdx.x * 4 + wave) * 16;
  char* ring_w = &ring[wave][0];

  // ---- A-fragment weights, register-resident.
  half8 wih[2][7];    // W_ih[16nt+c][32kb+8g+e]
  half8 whh[4][7];    // W_hh[16nt+c][phi(32kb+8g+e)]
  float4_t bias[7];   // (b_ih+b_hh)[16nt+4g+v]

  #pragma unroll
  for (int nt = 0; nt < 7; ++nt) {
    int nb = nt * 16 + 4 * g;
    float4_t bi = {0.f, 0.f, 0.f, 0.f};
    if (nb + 3 < 100) {
      float4_t a = *(const float4_t*)(b_ih + nb);
      float4_t b = *(const float4_t*)(b_hh + nb);
      bi = a + b;
    }
    bias[nt] = bi;

    int nrow = nt * 16 + c;
    bool rv = (nrow < 100);
    #pragma unroll
    for (int kb = 0; kb < 2; ++kb) {
      float4_t f0 = {0.f,0.f,0.f,0.f}, f1 = {0.f,0.f,0.f,0.f};
      if (rv) {
        const float* p = W_ih + nrow * 64 + kb * 32 + g * 8;
        f0 = *(const float4_t*)p;
        f1 = *(const float4_t*)(p + 4);
      }
      half8 h;
      #pragma unroll
      for (int j = 0; j < 4; ++j) { h[j] = (_Float16)f0[j]; h[4 + j] = (_Float16)f1[j]; }
      wih[kb][nt] = h;
    }
    #pragma unroll
    for (int kb = 0; kb < 4; ++kb) {
      int clo = kb * 32 + 4 * g;
      int chi = clo + 16;
      float4_t f0 = {0.f,0.f,0.f,0.f}, f1 = {0.f,0.f,0.f,0.f};
      if (rv && clo + 3 < 100) f0 = *(const float4_t*)(W_hh + nrow * 100 + clo);
      if (rv && chi + 3 < 100) f1 = *(const float4_t*)(W_hh + nrow * 100 + chi);
      half8 h;
      #pragma unroll
      for (int j = 0; j < 4; ++j) { h[j] = (_Float16)f0[j]; h[4 + j] = (_Float16)f1[j]; }
      whh[kb][nt] = h;
    }
  }

  // ---- per-lane DMA source pointers: chunk m = j*64+lane ->
  //      row r = m/17, chunk-in-row c17 = m%17 (c17==16 => pad, dummy src).
  //      LDS linear offset m*16 == r*272 + c17*16 (exact match, no scatter).
  const float* gsrc[5];
  #pragma unroll
  for (int j = 0; j < 5; ++j) {
    int m = j * 64 + lane;
    int r = (m * 3856) >> 16;       // m/17 for m<1000
    int c17 = m - r * 17;
    bool valid = (r < 16) & (c17 < 16);
    int row = rowbase + (valid ? r : 0);
    int col = valid ? c17 * 4 : 0;  // float index within the 64-float step block
    gsrc[j] = x + (size_t)row * 4096 + col;
  }

  // ---- prologue: fill slots 0,1,2 (steps 0..2) -> 15 loads outstanding
  #pragma unroll
  for (int s = 0; s < 3; ++s)
    #pragma unroll
    for (int j = 0; j < 5; ++j)
      GLOAD16(gsrc[j] + s * 64, ring_w + s * SLOT_BYTES + j * 1024);

  float4_t acc[7];
  half8 hfrag[4];
  #pragma unroll
  for (int kb = 0; kb < 4; ++kb) hfrag[kb] = (half8)(_Float16)0.0f;  // h_0 = 0

  const int roff = c * 272 + g * 32;   // lane's byte offset within a slot

  for (int t = 0; t < 64; ++t) {
    // issue slot t+3 (clamped source; constant 5 issues/step)
    int tp = t + 3; if (tp > 63) tp = 63;
    char* lb = ring_w + ((t + 3) & 3) * SLOT_BYTES;
    #pragma unroll
    for (int j = 0; j < 5; ++j)
      GLOAD16(gsrc[j] + tp * 64, lb + j * 1024);

    // slot t complete once the 15 newer loads are the only ones in flight
    asm volatile("s_waitcnt vmcnt(15)" ::: "memory");

    // xb source: 16 floats of x[row c][k=8g..8g+7, 32+8g..32+8g+7]
    const char* sp = ring_w + (t & 3) * SLOT_BYTES + roff;
    float4_t s0 = *(const float4_t*)(sp);
    float4_t s1 = *(const float4_t*)(sp + 16);
    float4_t s2 = *(const float4_t*)(sp + 128);
    float4_t s3 = *(const float4_t*)(sp + 144);

    // recurrence first (register-fed; hides ds_read latency)
    #pragma unroll
    for (int nt = 0; nt < 7; ++nt)
      acc[nt] = __builtin_amdgcn_mfma_f32_16x16x32_f16(whh[0][nt], hfrag[0], bias[nt], 0, 0, 0);
    #pragma unroll
    for (int kb = 1; kb < 4; ++kb)
      #pragma unroll
      for (int nt = 0; nt < 7; ++nt)
        acc[nt] = __builtin_amdgcn_mfma_f32_16x16x32_f16(whh[kb][nt], hfrag[kb], acc[nt], 0, 0, 0);

    // input projection
    half8 xb0, xb1;
    #pragma unroll
    for (int j = 0; j < 4; ++j) {
      xb0[j] = (_Float16)s0[j]; xb0[4 + j] = (_Float16)s1[j];
      xb1[j] = (_Float16)s2[j]; xb1[4 + j] = (_Float16)s3[j];
    }
    #pragma unroll
    for (int nt = 0; nt < 7; ++nt) {
      acc[nt] = __builtin_amdgcn_mfma_f32_16x16x32_f16(wih[0][nt], xb0, acc[nt], 0, 0, 0);
      acc[nt] = __builtin_amdgcn_mfma_f32_16x16x32_f16(wih[1][nt], xb1, acc[nt], 0, 0, 0);
    }

    // h_{t+1} = tanh(preact); D regs -> next B-frag via per-lane cvt only
    #pragma unroll
    for (int nt = 0; nt < 7; ++nt)
      #pragma unroll
      for (int v = 0; v < 4; ++v)
        acc[nt][v] = tanh_fast(acc[nt][v]);

    #pragma unroll
    for (int kb = 0; kb < 4; ++kb) {
      half8 h;
      #pragma unroll
      for (int v = 0; v < 4; ++v) {
        h[v] = (_Float16)acc[2 * kb][v];
        h[4 + v] = (kb < 3) ? (_Float16)acc[2 * kb + 1][v] : (_Float16)0.0f;
      }
      hfrag[kb] = h;
    }
  }

  // ---- epilogue: out^T = fc_W * tanh(h_last)^T + fc_b
  #pragma unroll
  for (int nt = 0; nt < 7; ++nt)
    #pragma unroll
    for (int v = 0; v < 4; ++v)
      acc[nt][v] = tanh_fast(acc[nt][v]);
  #pragma unroll
  for (int kb = 0; kb < 4; ++kb) {
    half8 h;
    #pragma unroll
    for (int v = 0; v < 4; ++v) {
      h[v] = (_Float16)acc[2 * kb][v];
      h[4 + v] = (kb < 3) ? (_Float16)acc[2 * kb + 1][v] : (_Float16)0.0f;
    }
    hfrag[kb] = h;
  }

  half8 wfc[4][3];
  float4_t bfc[3];
  #pragma unroll
  for (int nt = 0; nt < 3; ++nt) {
    int nb = nt * 16 + 4 * g;
    float4_t bi = {0.f,0.f,0.f,0.f};
    if (nb + 3 < 40) bi = *(const float4_t*)(fc_b + nb);
    bfc[nt] = bi;

    int nrow = nt * 16 + c;
    bool rv = (nrow < 40);
    #pragma unroll
    for (int kb = 0; kb < 4; ++kb) {
      int clo = kb * 32 + 4 * g;
      int chi = clo + 16;
      float4_t f0 = {0.f,0.f,0.f,0.f}, f1 = {0.f,0.f,0.f,0.f};
      if (rv && clo + 3 < 100) f0 = *(const float4_t*)(fc_W + nrow * 100 + clo);
      if (rv && chi + 3 < 100) f1 = *(const float4_t*)(fc_W + nrow * 100 + chi);
      half8 h;
      #pragma unroll
      for (int j = 0; j < 4; ++j) { h[j] = (_Float16)f0[j]; h[4 + j] = (_Float16)f1[j]; }
      wfc[kb][nt] = h;
    }
  }

  float4_t oacc[3];
  #pragma unroll
  for (int nt = 0; nt < 3; ++nt) oacc[nt] = bfc[nt];
  #pragma unroll
  for (int kb = 0; kb < 4; ++kb)
    #pragma unroll
    for (int nt = 0; nt < 3; ++nt)
      oacc[nt] = __builtin_amdgcn_mfma_f32_16x16x32_f16(wfc[kb][nt], hfrag[kb], oacc[nt], 0, 0, 0);

  // store: lane (g,c) holds out[rowbase+c][n = 16nt+4g+v]
  #pragma unroll
  for (int nt = 0; nt < 3; ++nt)
    #pragma unroll
    for (int v = 0; v < 4; ++v) {
      int n = nt * 16 + 4 * g + v;
      if (n < 40)
        out[(size_t)(rowbase + c) * 40 + n] = oacc[nt][v];
    }
}

extern "C" void kernel_launch(void* const* d_in, const int* in_sizes, int n_in,
                              void* d_out, int out_size, void* d_ws, size_t ws_size,
                              hipStream_t stream) {
  const float* x    = (const float*)d_in[0];
  const float* W_ih = (const float*)d_in[1];
  const float* W_hh = (const float*)d_in[2];
  const float* b_ih = (const float*)d_in[3];
  const float* b_hh = (const float*)d_in[4];
  const float* fc_W = (const float*)d_in[5];
  const float* fc_b = (const float*)d_in[6];
  float* outp = (float*)d_out;

  int B = in_sizes[0] / 4096;      // 16384
  int grid = (B + 63) / 64;        // 64 batch rows per 4-wave block
  rnn_fused<<<grid, 256, 0, stream>>>(x, W_ih, W_hh, b_ih, b_hh, fc_W, fc_b, outp, B);
}